// Round 3
// baseline (1611.952 us; speedup 1.0000x reference)
//
#include <hip/hip_runtime.h>
#include <hip/hip_bf16.h>
#include <stdint.h>

#define HW   16384
#define NB   64
#define WPER 28970
#define NBN  156
#define EPSB 1e-5f

__device__ __forceinline__ float bfr(uint16_t u){
    union { uint32_t i; float f; } v; v.i = ((uint32_t)u) << 16; return v.f;
}
// bn_var[0] is exactly 1.0: fp32 -> dword 0x3F800000, bf16 -> 0x3F803F80.
__device__ __forceinline__ int is_fp32(const void* bnvar){
    return *(const uint32_t*)bnvar == 0x3F800000u ? 1 : 0;
}
__device__ __forceinline__ float lda(const void* p, long i, int m){
    float v;
    if (m) v = ((const float*)p)[i];
    else   v = bfr(((const uint16_t*)p)[i]);
    return v;
}

// Gather all per-sample hypernet weights (either dtype) -> fp32 in ws.
__global__ void prep_w(const void* __restrict__ w1, const void* __restrict__ w2,
                       const void* __restrict__ w3, const void* __restrict__ w4,
                       const void* __restrict__ va, float* __restrict__ out)
{
    const int m = is_fp32(va);
    long tid = blockIdx.x * 256 + threadIdx.x;
    long total = (long)NB * WPER, stride = (long)gridDim.x * 256;
    for (long i = tid; i < total; i += stride) {
        int b = (int)(i / WPER), p = (int)(i - (long)b * WPER);
        const void* base; long src;
        if      (p <  3672) { base = w1; src = (long)b *  3672 +  p;          }
        else if (p < 16200) { base = w2; src = (long)b * 12528 + (p -  3672); }
        else if (p < 28728) { base = w3; src = (long)b * 12528 + (p - 16200); }
        else                { base = w4; src = (long)b *   242 + (p - 28728); }
        out[i] = lda(base, src, m);
    }
}

// Per-sample conv (+BN+ReLU unless FIN). BIG: weights pre-converted fp32
// (block-uniform -> scalar loads). !BIG: stage layer weights into LDS.
template<int CA, int CX, int CO, bool BIG, bool FIN>
__global__ __launch_bounds__(256)
void conv_k(const float* __restrict__ actIn, const void* __restrict__ xRaw,
            const float* __restrict__ wBig, const void* __restrict__ wRaw,
            long wOff, long wStride,
            const void* __restrict__ bg, const void* __restrict__ bb,
            const void* __restrict__ bm, const void* __restrict__ bv, int bnOff,
            float* __restrict__ actOut, float* __restrict__ outF, int b0)
{
    constexpr int CIN = CA + CX;
    constexpr int WSM = BIG ? 1 : (FIN ? CO * CIN : CIN * CO * 12);
    __shared__ float wsm[WSM];
    __shared__ float bnS[CO], bnB[CO];

    const int m  = is_fp32(bv);
    const int s  = blockIdx.y, gb = b0 + s;
    const int p  = blockIdx.x * 256 + threadIdx.x;
    const int y  = p >> 7, xc = p & 127;

    if (!FIN && threadIdx.x < CO) {
        int o = threadIdx.x;
        float gg = lda(bg, bnOff + o, m), be_ = lda(bb, bnOff + o, m);
        float mm = lda(bm, bnOff + o, m), vv  = lda(bv, bnOff + o, m);
        float sc = gg * rsqrtf(vv + EPSB);
        bnS[o] = sc; bnB[o] = be_ - mm * sc;
    }
    if constexpr (!BIG) {
        constexpr int nW = FIN ? CO * CIN : CO * CIN * 9;
        for (int i = threadIdx.x; i < nW; i += 256) {
            float w;
            if (m) w = ((const float*)wRaw)[(long)gb * wStride + wOff + i];
            else   w = bfr(((const uint16_t*)wRaw)[(long)gb * wStride + wOff + i]);
            if (FIN) { int o = i / CIN, c = i - o * CIN; wsm[c * CO + o] = w; }
            else     { int o = i / (CIN * 9); int r = i - o * (CIN * 9);
                       int c = r / 9, k = r - c * 9; wsm[(c * CO + o) * 12 + k] = w; }
        }
    }
    __syncthreads();

    const float* wb = nullptr;
    if constexpr (BIG) wb = wBig + (long)gb * WPER + wOff;

    float acc[CO];
#pragma unroll
    for (int o = 0; o < CO; ++o) acc[o] = 0.f;

    if constexpr (!FIN) {
        int idx[9]; float msk[9];
#pragma unroll
        for (int dy = -1; dy <= 1; ++dy)
#pragma unroll
            for (int dx = -1; dx <= 1; ++dx) {
                int yy = y + dy, xx = xc + dx;
                bool ok = ((unsigned)yy < 128u) && ((unsigned)xx < 128u);
                int k = (dy + 1) * 3 + (dx + 1);
                idx[k] = ok ? ((yy << 7) + xx) : 0;
                msk[k] = ok ? 1.f : 0.f;
            }
#pragma unroll 1
        for (int c = 0; c < CA; ++c) {
            const float* ip = actIn + ((long)s * CA + c) * HW;
            float v[9];
#pragma unroll
            for (int k = 0; k < 9; ++k) v[k] = ip[idx[k]] * msk[k];
#pragma unroll
            for (int o = 0; o < CO; ++o)
#pragma unroll
                for (int k = 0; k < 9; ++k) {
                    float w = BIG ? wb[(o * CIN + c) * 9 + k] : wsm[(c * CO + o) * 12 + k];
                    acc[o] = fmaf(w, v[k], acc[o]);
                }
        }
#pragma unroll 1
        for (int c = 0; c < CX; ++c) {
            long base = ((long)gb * 10 + c) * HW;
            float v[9];
            if (m) {
                const float* xp = (const float*)xRaw;
#pragma unroll
                for (int k = 0; k < 9; ++k) v[k] = xp[base + idx[k]] * msk[k];
            } else {
                const uint16_t* xp = (const uint16_t*)xRaw;
#pragma unroll
                for (int k = 0; k < 9; ++k) v[k] = bfr(xp[base + idx[k]]) * msk[k];
            }
            int ci = CA + c;
#pragma unroll
            for (int o = 0; o < CO; ++o)
#pragma unroll
                for (int k = 0; k < 9; ++k) {
                    float w = BIG ? wb[(o * CIN + ci) * 9 + k] : wsm[(ci * CO + o) * 12 + k];
                    acc[o] = fmaf(w, v[k], acc[o]);
                }
        }
    } else {  // 1x1
#pragma unroll 1
        for (int c = 0; c < CA; ++c) {
            float v = actIn[((long)s * CA + c) * HW + p];
#pragma unroll
            for (int o = 0; o < CO; ++o) {
                float w = BIG ? wb[o * CIN + c] : wsm[c * CO + o];
                acc[o] = fmaf(w, v, acc[o]);
            }
        }
#pragma unroll 1
        for (int c = 0; c < CX; ++c) {
            float v = lda(xRaw, ((long)gb * 10 + c) * HW + p, m);
            int ci = CA + c;
#pragma unroll
            for (int o = 0; o < CO; ++o) {
                float w = BIG ? wb[o * CIN + ci] : wsm[ci * CO + o];
                acc[o] = fmaf(w, v, acc[o]);
            }
        }
    }

#pragma unroll
    for (int o = 0; o < CO; ++o) {
        if constexpr (FIN)
            outF[((long)gb * CO + o) * HW + p] = acc[o];   // fp32 output!
        else {
            float r = fmaf(acc[o], bnS[o], bnB[o]);
            actOut[((long)s * CO + o) * HW + p] = fmaxf(r, 0.f);
        }
    }
}

extern "C" void kernel_launch(void* const* d_in, const int* in_sizes, int n_in,
                              void* d_out, int out_size, void* d_ws, size_t ws_size,
                              hipStream_t stream)
{
    // Identify inputs by size signature (fallback: dict order).
    const void *x = d_in[0], *w1 = d_in[1], *w2 = d_in[2], *w3 = d_in[3],
               *w4 = d_in[4], *g = d_in[5], *be = d_in[6], *mu = d_in[7], *va = d_in[8];
    if (n_in == 9) {
        const void* big801[2] = {nullptr, nullptr}; int n801 = 0;
        const void* bn156[4]  = {nullptr, nullptr, nullptr, nullptr}; int n156 = 0;
        const void *fx = nullptr, *fw1 = nullptr, *fw4 = nullptr;
        for (int i = 0; i < 9; ++i) {
            int sz = in_sizes[i];
            if      (sz == 10485760) fx = d_in[i];
            else if (sz ==   235008) fw1 = d_in[i];
            else if (sz ==   801792) { if (n801 < 2) big801[n801++] = d_in[i]; }
            else if (sz ==    15488) fw4 = d_in[i];
            else if (sz ==      156) { if (n156 < 4) bn156[n156++] = d_in[i]; }
        }
        if (fx && fw1 && fw4 && n801 == 2 && n156 == 4) {
            x = fx; w1 = fw1; w2 = big801[0]; w3 = big801[1]; w4 = fw4;
            g = bn156[0]; be = bn156[1]; mu = bn156[2]; va = bn156[3];
        }
    }
    float* out = (float*)d_out;

    const size_t wgtB = (size_t)NB * WPER * 4;        // 7,416,320 B
    const size_t per2 = 2ull * 24 * HW * 4;           // ping+pong per sample
    const bool   big  = ws_size >= wgtB + per2 + 4096;

    float* wcvt  = (float*)d_ws;
    float* acts  = big ? (float*)((char*)d_ws + wgtB) : (float*)d_ws;
    size_t avail = big ? ws_size - wgtB : ws_size;
    int chunk = (int)(avail / per2);
    if (chunk > NB) chunk = NB;
    if (chunk < 1)  chunk = 1;
    float* bufA = acts;
    float* bufB = bufA + (size_t)chunk * 24 * HW;

    if (big) prep_w<<<2048, 256, 0, stream>>>(w1, w2, w3, w4, va, wcvt);

    for (int b0 = 0; b0 < NB; b0 += chunk) {
        int nb = (NB - b0 < chunk) ? (NB - b0) : chunk;
        dim3 gr(64, nb);
        if (big) {
            conv_k< 0,10,12,true ,false><<<gr,256,0,stream>>>(nullptr, x, wcvt, nullptr,     0, WPER, g,be,mu,va,   0, bufA, nullptr, b0);
            conv_k<12, 0,12,true ,false><<<gr,256,0,stream>>>(bufA,    x, wcvt, nullptr,  1080, WPER, g,be,mu,va,  12, bufB, nullptr, b0);
            conv_k<12, 0,12,true ,false><<<gr,256,0,stream>>>(bufB,    x, wcvt, nullptr,  2376, WPER, g,be,mu,va,  24, bufA, nullptr, b0);
            conv_k<12,10,24,true ,false><<<gr,256,0,stream>>>(bufA,    x, wcvt, nullptr,  3672, WPER, g,be,mu,va,  36, bufB, nullptr, b0);
            conv_k<24, 0,24,true ,false><<<gr,256,0,stream>>>(bufB,    x, wcvt, nullptr,  8424, WPER, g,be,mu,va,  60, bufA, nullptr, b0);
            conv_k<24, 0,12,true ,false><<<gr,256,0,stream>>>(bufA,    x, wcvt, nullptr, 13608, WPER, g,be,mu,va,  84, bufB, nullptr, b0);
            conv_k<12,10,24,true ,false><<<gr,256,0,stream>>>(bufB,    x, wcvt, nullptr, 16200, WPER, g,be,mu,va,  96, bufA, nullptr, b0);
            conv_k<24, 0,24,true ,false><<<gr,256,0,stream>>>(bufA,    x, wcvt, nullptr, 20952, WPER, g,be,mu,va, 120, bufB, nullptr, b0);
            conv_k<24, 0,12,true ,false><<<gr,256,0,stream>>>(bufB,    x, wcvt, nullptr, 26136, WPER, g,be,mu,va, 144, bufA, nullptr, b0);
            conv_k<12,10,11,true ,true ><<<gr,256,0,stream>>>(bufA,    x, wcvt, nullptr, 28728, WPER, g,be,mu,va,   0, nullptr, out, b0);
        } else {
            conv_k< 0,10,12,false,false><<<gr,256,0,stream>>>(nullptr, x, nullptr, w1,    0,  3672, g,be,mu,va,   0, bufA, nullptr, b0);
            conv_k<12, 0,12,false,false><<<gr,256,0,stream>>>(bufA,    x, nullptr, w1, 1080,  3672, g,be,mu,va,  12, bufB, nullptr, b0);
            conv_k<12, 0,12,false,false><<<gr,256,0,stream>>>(bufB,    x, nullptr, w1, 2376,  3672, g,be,mu,va,  24, bufA, nullptr, b0);
            conv_k<12,10,24,false,false><<<gr,256,0,stream>>>(bufA,    x, nullptr, w2,    0, 12528, g,be,mu,va,  36, bufB, nullptr, b0);
            conv_k<24, 0,24,false,false><<<gr,256,0,stream>>>(bufB,    x, nullptr, w2, 4752, 12528, g,be,mu,va,  60, bufA, nullptr, b0);
            conv_k<24, 0,12,false,false><<<gr,256,0,stream>>>(bufA,    x, nullptr, w2, 9936, 12528, g,be,mu,va,  84, bufB, nullptr, b0);
            conv_k<12,10,24,false,false><<<gr,256,0,stream>>>(bufB,    x, nullptr, w3,    0, 12528, g,be,mu,va,  96, bufA, nullptr, b0);
            conv_k<24, 0,24,false,false><<<gr,256,0,stream>>>(bufA,    x, nullptr, w3, 4752, 12528, g,be,mu,va, 120, bufB, nullptr, b0);
            conv_k<24, 0,12,false,false><<<gr,256,0,stream>>>(bufB,    x, nullptr, w3, 9936, 12528, g,be,mu,va, 144, bufA, nullptr, b0);
            conv_k<12,10,11,false,true ><<<gr,256,0,stream>>>(bufA,    x, nullptr, w4,    0,   242, g,be,mu,va,   0, nullptr, out, b0);
        }
    }
}

// Round 4
// 1375.909 us; speedup vs baseline: 1.1716x; 1.1716x over previous
//
#include <hip/hip_runtime.h>
#include <stdint.h>

#define HW    16384
#define NB    64
#define WPER  28970
#define NBIAS 156
#define EPSB  1e-5f

// Gather per-sample hypernet weights -> fp32 ws, folding the BN scale
// (gamma*rsqrt(var+eps)) of each conv's output channel into the weights.
// Also emit per-channel bias = beta - mean*scale.
__global__ void prep_w(const float* __restrict__ w1, const float* __restrict__ w2,
                       const float* __restrict__ w3, const float* __restrict__ w4,
                       const float* __restrict__ g,  const float* __restrict__ be,
                       const float* __restrict__ mu, const float* __restrict__ va,
                       float* __restrict__ wout, float* __restrict__ bias)
{
    const int start[11] = {0,1080,2376,3672,8424,13608,16200,20952,26136,28728,28970};
    const int cink[10]  = {90,108,108,198,216,216,198,216,216,22};   // CIN*9 (final: CIN)
    const int bnoff[10] = {0,12,24,36,60,84,96,120,144,0};
    long tid = (long)blockIdx.x * 256 + threadIdx.x;
    long total = (long)NB * WPER, stride = (long)gridDim.x * 256;
    for (long i = tid; i < total; i += stride) {
        int b = (int)(i / WPER), p = (int)(i - (long)b * WPER);
        const float* src; long si;
        if      (p <  3672) { src = w1; si = (long)b *  3672 +  p;          }
        else if (p < 16200) { src = w2; si = (long)b * 12528 + (p -  3672); }
        else if (p < 28728) { src = w3; si = (long)b * 12528 + (p - 16200); }
        else                { src = w4; si = (long)b *   242 + (p - 28728); }
        float w = src[si];
        int l = 0;
        while (p >= start[l + 1]) ++l;
        if (l < 9) {  // layers 0..8 have BN; final 1x1 does not
            int o  = (p - start[l]) / cink[l];
            int bi = bnoff[l] + o;
            w *= g[bi] * rsqrtf(va[bi] + EPSB);
        }
        wout[i] = w;
    }
    if (tid < NBIAS) {
        float s = g[tid] * rsqrtf(va[tid] + EPSB);
        bias[tid] = be[tid] - mu[tid] * s;
    }
}

// Per-sample 3x3 conv (+folded BN, ReLU). Each thread: 2 vertically-adjacent
// pixels (12 taps -> 2*CO*9 FMAs). Weights block-uniform -> scalar loads.
template<int CA, int CX, int CO>
__global__ __launch_bounds__(256, 4)
void conv3(const float* __restrict__ actIn, const float* __restrict__ xIn,
           const float* __restrict__ wAll, int wOff,
           const float* __restrict__ bias, int bnOff,
           float* __restrict__ actOut, int b0)
{
    constexpr int CIN = CA + CX;
    const int s  = blockIdx.y, gb = b0 + s;
    const int t  = threadIdx.x;
    const int xc = t & 127;
    const int y0 = blockIdx.x * 4 + ((t >> 7) << 1);   // rows y0, y0+1

    // 12 taps: rows y0-1..y0+2  x  cols xc-1..xc+1 (clamped idx + zero mask)
    int off[12]; float msk[12];
#pragma unroll
    for (int rr = 0; rr < 4; ++rr) {
        int r = y0 - 1 + rr;
        bool rok = (unsigned)r < 128u;
        int rc = rok ? r : (r < 0 ? 0 : 127);
#pragma unroll
        for (int cc = 0; cc < 3; ++cc) {
            int cl = xc - 1 + cc;
            bool cok = (unsigned)cl < 128u;
            int cv = cok ? cl : (cl < 0 ? 0 : 127);
            off[rr * 3 + cc] = rc * 128 + cv;
            msk[rr * 3 + cc] = (rok && cok) ? 1.f : 0.f;
        }
    }

    const float* __restrict__ wb = wAll + (long)gb * WPER + wOff;

    float acc[2 * CO];
#pragma unroll
    for (int o = 0; o < CO; ++o) {
        float b_ = bias[bnOff + o];
        acc[o] = b_; acc[CO + o] = b_;
    }

#pragma unroll 1
    for (int c = 0; c < CA; ++c) {
        const float* __restrict__ ip = actIn + ((long)s * CA + c) * HW;
        float tp[12];
#pragma unroll
        for (int i = 0; i < 12; ++i) tp[i] = ip[off[i]] * msk[i];
        const float* __restrict__ wc = wb + c * 9;
#pragma unroll
        for (int o = 0; o < CO; ++o)
#pragma unroll
            for (int kr = 0; kr < 3; ++kr)
#pragma unroll
                for (int kc = 0; kc < 3; ++kc) {
                    float w = wc[o * CIN * 9 + kr * 3 + kc];
                    acc[o]      = fmaf(w, tp[kr * 3 + kc],       acc[o]);
                    acc[CO + o] = fmaf(w, tp[(kr + 1) * 3 + kc], acc[CO + o]);
                }
    }
#pragma unroll 1
    for (int c = 0; c < CX; ++c) {
        const float* __restrict__ ip = xIn + ((long)gb * 10 + c) * HW;
        float tp[12];
#pragma unroll
        for (int i = 0; i < 12; ++i) tp[i] = ip[off[i]] * msk[i];
        const float* __restrict__ wc = wb + (CA + c) * 9;
#pragma unroll
        for (int o = 0; o < CO; ++o)
#pragma unroll
            for (int kr = 0; kr < 3; ++kr)
#pragma unroll
                for (int kc = 0; kc < 3; ++kc) {
                    float w = wc[o * CIN * 9 + kr * 3 + kc];
                    acc[o]      = fmaf(w, tp[kr * 3 + kc],       acc[o]);
                    acc[CO + o] = fmaf(w, tp[(kr + 1) * 3 + kc], acc[CO + o]);
                }
    }

    long obase = (long)s * CO * HW + y0 * 128 + xc;
#pragma unroll
    for (int o = 0; o < CO; ++o) {
        actOut[obase + (long)o * HW]       = fmaxf(acc[o], 0.f);
        actOut[obase + (long)o * HW + 128] = fmaxf(acc[CO + o], 0.f);
    }
}

// Final per-sample 1x1 conv, no BN/ReLU, fp32 output.
template<int CA, int CX, int CO>
__global__ __launch_bounds__(256, 4)
void conv1x1(const float* __restrict__ actIn, const float* __restrict__ xIn,
             const float* __restrict__ wAll, int wOff,
             float* __restrict__ outF, int b0)
{
    constexpr int CIN = CA + CX;
    const int s = blockIdx.y, gb = b0 + s;
    const int p = blockIdx.x * 256 + threadIdx.x;
    const float* __restrict__ wb = wAll + (long)gb * WPER + wOff;

    float acc[CO];
#pragma unroll
    for (int o = 0; o < CO; ++o) acc[o] = 0.f;

#pragma unroll 1
    for (int c = 0; c < CA; ++c) {
        float v = actIn[((long)s * CA + c) * HW + p];
#pragma unroll
        for (int o = 0; o < CO; ++o) acc[o] = fmaf(wb[o * CIN + c], v, acc[o]);
    }
#pragma unroll 1
    for (int c = 0; c < CX; ++c) {
        float v = xIn[((long)gb * 10 + c) * HW + p];
#pragma unroll
        for (int o = 0; o < CO; ++o) acc[o] = fmaf(wb[o * CIN + CA + c], v, acc[o]);
    }
#pragma unroll
    for (int o = 0; o < CO; ++o)
        outF[((long)gb * CO + o) * HW + p] = acc[o];
}

extern "C" void kernel_launch(void* const* d_in, const int* in_sizes, int n_in,
                              void* d_out, int out_size, void* d_ws, size_t ws_size,
                              hipStream_t stream)
{
    // Identify inputs by size signature (fallback: dict order).
    const float *x = (const float*)d_in[0], *w1 = (const float*)d_in[1],
                *w2 = (const float*)d_in[2], *w3 = (const float*)d_in[3],
                *w4 = (const float*)d_in[4], *g  = (const float*)d_in[5],
                *be = (const float*)d_in[6], *mu = (const float*)d_in[7],
                *va = (const float*)d_in[8];
    if (n_in == 9) {
        const float* big801[2] = {nullptr, nullptr}; int n801 = 0;
        const float* bn156[4]  = {nullptr, nullptr, nullptr, nullptr}; int n156 = 0;
        const float *fx = nullptr, *fw1 = nullptr, *fw4 = nullptr;
        for (int i = 0; i < 9; ++i) {
            int sz = in_sizes[i];
            if      (sz == 10485760) fx  = (const float*)d_in[i];
            else if (sz ==   235008) fw1 = (const float*)d_in[i];
            else if (sz ==   801792) { if (n801 < 2) big801[n801++] = (const float*)d_in[i]; }
            else if (sz ==    15488) fw4 = (const float*)d_in[i];
            else if (sz ==      156) { if (n156 < 4) bn156[n156++] = (const float*)d_in[i]; }
        }
        if (fx && fw1 && fw4 && n801 == 2 && n156 == 4) {
            x = fx; w1 = fw1; w2 = big801[0]; w3 = big801[1]; w4 = fw4;
            g = bn156[0]; be = bn156[1]; mu = bn156[2]; va = bn156[3];
        }
    }
    float* out = (float*)d_out;

    const size_t wgtB  = (size_t)NB * WPER * 4;                 // 7,416,320 B
    const size_t biasB = 1024;
    const size_t per2  = 2ull * 24 * HW * 4;                    // ping+pong per sample
    float* wcvt = (float*)d_ws;
    float* bias = (float*)((char*)d_ws + wgtB);
    size_t hdr  = wgtB + biasB;
    size_t avail = ws_size > hdr ? ws_size - hdr : per2;
    int chunk = (int)(avail / per2);
    if (chunk > NB) chunk = NB;
    if (chunk < 1)  chunk = 1;
    float* bufA = (float*)((char*)d_ws + hdr);
    float* bufB = bufA + (size_t)chunk * 24 * HW;

    prep_w<<<2048, 256, 0, stream>>>(w1, w2, w3, w4, g, be, mu, va, wcvt, bias);

    for (int b0 = 0; b0 < NB; b0 += chunk) {
        int nb = (NB - b0 < chunk) ? (NB - b0) : chunk;
        dim3 g3(32, nb);    // 32 blocks x 4 rows = 128 rows
        dim3 g1(64, nb);
        conv3< 0,10,12><<<g3,256,0,stream>>>(nullptr, x, wcvt,     0, bias,   0, bufA, b0);
        conv3<12, 0,12><<<g3,256,0,stream>>>(bufA,    x, wcvt,  1080, bias,  12, bufB, b0);
        conv3<12, 0,12><<<g3,256,0,stream>>>(bufB,    x, wcvt,  2376, bias,  24, bufA, b0);
        conv3<12,10,24><<<g3,256,0,stream>>>(bufA,    x, wcvt,  3672, bias,  36, bufB, b0);
        conv3<24, 0,24><<<g3,256,0,stream>>>(bufB,    x, wcvt,  8424, bias,  60, bufA, b0);
        conv3<24, 0,12><<<g3,256,0,stream>>>(bufA,    x, wcvt, 13608, bias,  84, bufB, b0);
        conv3<12,10,24><<<g3,256,0,stream>>>(bufB,    x, wcvt, 16200, bias,  96, bufA, b0);
        conv3<24, 0,24><<<g3,256,0,stream>>>(bufA,    x, wcvt, 20952, bias, 120, bufB, b0);
        conv3<24, 0,12><<<g3,256,0,stream>>>(bufB,    x, wcvt, 26136, bias, 144, bufA, b0);
        conv1x1<12,10,11><<<g1,256,0,stream>>>(bufA,  x, wcvt, 28728, out, b0);
    }
}

// Round 5
// 936.309 us; speedup vs baseline: 1.7216x; 1.4695x over previous
//
#include <hip/hip_runtime.h>
#include <stdint.h>

#define HW    16384
#define NB    64
#define WPER  28970
#define NBIAS 156
#define EPSB  1e-5f
#define PROW  132            // padded row stride (floats): 1 left + 128 + 3 right
#define PLSZ  (130*132)      // padded plane: 130 rows x 132 cols = 17160 floats

typedef float f4 __attribute__((ext_vector_type(4)));
typedef f4 uf4 __attribute__((aligned(4)));   // 4-byte-aligned float4 loads

// ---- prep: gather per-sample weights -> fp32 ws, fold BN scale into weights.
__global__ void prep_w(const float* __restrict__ w1, const float* __restrict__ w2,
                       const float* __restrict__ w3, const float* __restrict__ w4,
                       const float* __restrict__ g,  const float* __restrict__ be,
                       const float* __restrict__ mu, const float* __restrict__ va,
                       float* __restrict__ wout, float* __restrict__ bias)
{
    const int start[11] = {0,1080,2376,3672,8424,13608,16200,20952,26136,28728,28970};
    const int cink[10]  = {90,108,108,198,216,216,198,216,216,22};
    const int bnoff[10] = {0,12,24,36,60,84,96,120,144,0};
    long tid = (long)blockIdx.x * 256 + threadIdx.x;
    long total = (long)NB * WPER, stride = (long)gridDim.x * 256;
    for (long i = tid; i < total; i += stride) {
        int b = (int)(i / WPER), p = (int)(i - (long)b * WPER);
        const float* src; long si;
        if      (p <  3672) { src = w1; si = (long)b *  3672 +  p;          }
        else if (p < 16200) { src = w2; si = (long)b * 12528 + (p -  3672); }
        else if (p < 28728) { src = w3; si = (long)b * 12528 + (p - 16200); }
        else                { src = w4; si = (long)b *   242 + (p - 28728); }
        float w = src[si];
        int l = 0;
        while (p >= start[l + 1]) ++l;
        if (l < 9) {
            int o  = (p - start[l]) / cink[l];
            int bi = bnoff[l] + o;
            w *= g[bi] * rsqrtf(va[bi] + EPSB);
        }
        wout[i] = w;
    }
    if (tid < NBIAS) {
        float s = g[tid] * rsqrtf(va[tid] + EPSB);
        bias[tid] = be[tid] - mu[tid] * s;
    }
}

// ---- copy x (64x10 planes, 128x128) into zero-padded 130x132 planes.
__global__ void pad_x(const float* __restrict__ x, float* __restrict__ padx)
{
    int plane = blockIdx.x;                       // b*10 + ch, 640 planes
    const float* __restrict__ src = x + (long)plane * HW;
    float* __restrict__ dst = padx + (long)plane * PLSZ;
    for (int i = threadIdx.x; i < PLSZ; i += 256) {
        int r = i / PROW, c = i - r * PROW;
        float v = 0.f;
        if (r >= 1 && r <= 128 && c >= 1 && c <= 128)
            v = src[(r - 1) * 128 + (c - 1)];
        dst[i] = v;
    }
}

// ---- zero the borders of nplanes padded planes (interiors are overwritten).
__global__ void zero_borders(float* __restrict__ base)
{
    float* __restrict__ p = base + (long)blockIdx.x * PLSZ;
    for (int j = threadIdx.x; j < 776; j += 256) {
        int idx;
        if      (j < 132) idx = j;                              // row 0
        else if (j < 264) idx = 129 * PROW + (j - 132);         // row 129
        else { int k = j - 264; int r = 1 + (k >> 2); int c4 = k & 3;
               idx = r * PROW + (c4 == 0 ? 0 : 128 + c4); }     // cols 0,129,130,131
        p[idx] = 0.f;
    }
}

// ---- per-sample 3x3 conv (+folded BN, ReLU), padded in/out planes.
// Thread: 2 horizontal px. Per channel: 3 dwordx4 tap loads -> 2*CO*9 FMAs.
template<int CA, int CX, int CO>
__global__ __launch_bounds__(256, 4)
void conv3(const float* __restrict__ actIn, const float* __restrict__ padx,
           const float* __restrict__ wAll, int wOff,
           const float* __restrict__ bias, int bnOff,
           float* __restrict__ actOut, int b0)
{
    constexpr int CIN = CA + CX;
    const int s  = blockIdx.y, gb = b0 + s;
    const int t  = threadIdx.x;
    const int xc = t & 63;                      // 64 threads x 2 px = 128 cols
    const int y  = blockIdx.x * 4 + (t >> 6);   // interior row 0..127
    const int tap0 = y * PROW + 2 * xc;         // padded row y, padded col 2xc

    const float* __restrict__ wb = wAll + (long)gb * WPER + wOff;

    float acc[2 * CO];
#pragma unroll
    for (int o = 0; o < CO; ++o) {
        float b_ = bias[bnOff + o];
        acc[2 * o] = b_; acc[2 * o + 1] = b_;
    }

#pragma unroll 1
    for (int c = 0; c < CA; ++c) {
        const float* __restrict__ ip = actIn + ((long)s * CA + c) * PLSZ + tap0;
        f4 t0 = *(const uf4*)(ip);
        f4 t1 = *(const uf4*)(ip + PROW);
        f4 t2 = *(const uf4*)(ip + 2 * PROW);
        float tp[12] = {t0.x,t0.y,t0.z,t0.w, t1.x,t1.y,t1.z,t1.w, t2.x,t2.y,t2.z,t2.w};
        const float* __restrict__ wc = wb + c * 9;
#pragma unroll
        for (int o = 0; o < CO; ++o) {
            const float* __restrict__ w9 = wc + o * CIN * 9;
#pragma unroll
            for (int kr = 0; kr < 3; ++kr)
#pragma unroll
                for (int kc = 0; kc < 3; ++kc) {
                    float w = w9[kr * 3 + kc];
                    acc[2 * o]     = fmaf(w, tp[kr * 4 + kc],     acc[2 * o]);
                    acc[2 * o + 1] = fmaf(w, tp[kr * 4 + kc + 1], acc[2 * o + 1]);
                }
        }
    }
#pragma unroll 1
    for (int c = 0; c < CX; ++c) {
        const float* __restrict__ ip = padx + ((long)gb * 10 + c) * PLSZ + tap0;
        f4 t0 = *(const uf4*)(ip);
        f4 t1 = *(const uf4*)(ip + PROW);
        f4 t2 = *(const uf4*)(ip + 2 * PROW);
        float tp[12] = {t0.x,t0.y,t0.z,t0.w, t1.x,t1.y,t1.z,t1.w, t2.x,t2.y,t2.z,t2.w};
        const float* __restrict__ wc = wb + (CA + c) * 9;
#pragma unroll
        for (int o = 0; o < CO; ++o) {
            const float* __restrict__ w9 = wc + o * CIN * 9;
#pragma unroll
            for (int kr = 0; kr < 3; ++kr)
#pragma unroll
                for (int kc = 0; kc < 3; ++kc) {
                    float w = w9[kr * 3 + kc];
                    acc[2 * o]     = fmaf(w, tp[kr * 4 + kc],     acc[2 * o]);
                    acc[2 * o + 1] = fmaf(w, tp[kr * 4 + kc + 1], acc[2 * o + 1]);
                }
        }
    }

    long obase = (long)s * CO * PLSZ + (y + 1) * PROW + 2 * xc + 1;
#pragma unroll
    for (int o = 0; o < CO; ++o) {
        actOut[obase + (long)o * PLSZ]     = fmaxf(acc[2 * o], 0.f);
        actOut[obase + (long)o * PLSZ + 1] = fmaxf(acc[2 * o + 1], 0.f);
    }
}

// ---- final per-sample 1x1 conv, padded inputs, unpadded fp32 output.
template<int CA, int CX, int CO>
__global__ __launch_bounds__(256, 4)
void conv1x1(const float* __restrict__ actIn, const float* __restrict__ padx,
             const float* __restrict__ wAll, int wOff,
             float* __restrict__ outF, int b0)
{
    constexpr int CIN = CA + CX;
    const int s = blockIdx.y, gb = b0 + s;
    const int p = blockIdx.x * 256 + threadIdx.x;
    const int off = ((p >> 7) + 1) * PROW + (p & 127) + 1;
    const float* __restrict__ wb = wAll + (long)gb * WPER + wOff;

    float acc[CO];
#pragma unroll
    for (int o = 0; o < CO; ++o) acc[o] = 0.f;

#pragma unroll 1
    for (int c = 0; c < CA; ++c) {
        float v = actIn[((long)s * CA + c) * PLSZ + off];
#pragma unroll
        for (int o = 0; o < CO; ++o) acc[o] = fmaf(wb[o * CIN + c], v, acc[o]);
    }
#pragma unroll 1
    for (int c = 0; c < CX; ++c) {
        float v = padx[((long)gb * 10 + c) * PLSZ + off];
#pragma unroll
        for (int o = 0; o < CO; ++o) acc[o] = fmaf(wb[o * CIN + CA + c], v, acc[o]);
    }
#pragma unroll
    for (int o = 0; o < CO; ++o)
        outF[((long)gb * CO + o) * HW + p] = acc[o];
}

extern "C" void kernel_launch(void* const* d_in, const int* in_sizes, int n_in,
                              void* d_out, int out_size, void* d_ws, size_t ws_size,
                              hipStream_t stream)
{
    const float *x = (const float*)d_in[0], *w1 = (const float*)d_in[1],
                *w2 = (const float*)d_in[2], *w3 = (const float*)d_in[3],
                *w4 = (const float*)d_in[4], *g  = (const float*)d_in[5],
                *be = (const float*)d_in[6], *mu = (const float*)d_in[7],
                *va = (const float*)d_in[8];
    if (n_in == 9) {   // identify by size signature (fallback: dict order)
        const float* big801[2] = {nullptr, nullptr}; int n801 = 0;
        const float* bn156[4]  = {nullptr, nullptr, nullptr, nullptr}; int n156 = 0;
        const float *fx = nullptr, *fw1 = nullptr, *fw4 = nullptr;
        for (int i = 0; i < 9; ++i) {
            int sz = in_sizes[i];
            if      (sz == 10485760) fx  = (const float*)d_in[i];
            else if (sz ==   235008) fw1 = (const float*)d_in[i];
            else if (sz ==   801792) { if (n801 < 2) big801[n801++] = (const float*)d_in[i]; }
            else if (sz ==    15488) fw4 = (const float*)d_in[i];
            else if (sz ==      156) { if (n156 < 4) bn156[n156++] = (const float*)d_in[i]; }
        }
        if (fx && fw1 && fw4 && n801 == 2 && n156 == 4) {
            x = fx; w1 = fw1; w2 = big801[0]; w3 = big801[1]; w4 = fw4;
            g = bn156[0]; be = bn156[1]; mu = bn156[2]; va = bn156[3];
        }
    }
    float* out = (float*)d_out;

    // ws layout: [weights 7.42MB][bias 1KB][padx 43.9MB][bufA|bufB (padded)]
    const size_t wgtB  = (size_t)NB * WPER * 4;
    const size_t biasB = 1024;
    const size_t padxB = (size_t)NB * 10 * PLSZ * 4;
    const size_t hdr   = wgtB + biasB + padxB;
    const size_t per2  = 2ull * 24 * PLSZ * 4;      // ping+pong per sample
    float* wcvt  = (float*)d_ws;
    float* bias  = (float*)((char*)d_ws + wgtB);
    float* padx  = (float*)((char*)d_ws + wgtB + biasB);
    size_t avail = ws_size > hdr ? ws_size - hdr : per2;
    int chunk = (int)(avail / per2);
    if (chunk > NB) chunk = NB;
    if (chunk < 1)  chunk = 1;
    float* bufA = (float*)((char*)d_ws + hdr);
    float* bufB = bufA + (size_t)chunk * 24 * PLSZ;

    prep_w<<<2048, 256, 0, stream>>>(w1, w2, w3, w4, g, be, mu, va, wcvt, bias);
    pad_x<<<NB * 10, 256, 0, stream>>>(x, padx);
    zero_borders<<<chunk * 48, 256, 0, stream>>>(bufA);   // bufA+bufB contiguous

    for (int b0 = 0; b0 < NB; b0 += chunk) {
        int nb = (NB - b0 < chunk) ? (NB - b0) : chunk;
        dim3 g3(32, nb);    // 32 row-tiles x 4 rows
        dim3 g1(64, nb);
        conv3< 0,10,12><<<g3,256,0,stream>>>(bufA,  padx, wcvt,     0, bias,   0, bufA, b0);
        conv3<12, 0,12><<<g3,256,0,stream>>>(bufA,  padx, wcvt,  1080, bias,  12, bufB, b0);
        conv3<12, 0,12><<<g3,256,0,stream>>>(bufB,  padx, wcvt,  2376, bias,  24, bufA, b0);
        conv3<12,10,24><<<g3,256,0,stream>>>(bufA,  padx, wcvt,  3672, bias,  36, bufB, b0);
        conv3<24, 0,24><<<g3,256,0,stream>>>(bufB,  padx, wcvt,  8424, bias,  60, bufA, b0);
        conv3<24, 0,12><<<g3,256,0,stream>>>(bufA,  padx, wcvt, 13608, bias,  84, bufB, b0);
        conv3<12,10,24><<<g3,256,0,stream>>>(bufB,  padx, wcvt, 16200, bias,  96, bufA, b0);
        conv3<24, 0,24><<<g3,256,0,stream>>>(bufA,  padx, wcvt, 20952, bias, 120, bufB, b0);
        conv3<24, 0,12><<<g3,256,0,stream>>>(bufB,  padx, wcvt, 26136, bias, 144, bufA, b0);
        conv1x1<12,10,11><<<g1,256,0,stream>>>(bufA, padx, wcvt, 28728, out, b0);
    }
}